// Round 1
// baseline (2475.591 us; speedup 1.0000x reference)
//
#include <hip/hip_runtime.h>

#define H 128

// ---------------------------------------------------------------- zero fill
__global__ void zero_f32(float* __restrict__ p, size_t n) {
  size_t i = (size_t)blockIdx.x * blockDim.x + threadIdx.x;
  size_t s = (size_t)gridDim.x * blockDim.x;
  for (; i < n; i += s) p[i] = 0.0f;
}

// ---------------------------------------------------------------- degrees
__global__ void deg_kernel(const int* __restrict__ src, const int* __restrict__ dst,
                           float* __restrict__ deg_e, float* __restrict__ deg_t, int E) {
  int i = blockIdx.x * blockDim.x + threadIdx.x;
  int s = gridDim.x * blockDim.x;
  for (; i < E; i += s) {
    atomicAdd(&deg_t[dst[i]], 1.0f);
    atomicAdd(&deg_e[src[i]], 1.0f);
  }
}

// ------------------------------------------------- scatter both directions
// per edge e: agg_t[dst[e]] += feat_e[src[e]];  agg_e[src[e]] += feat_t[dst[e]]
// one wave (64 lanes) per edge, 2 floats per lane.
__global__ void scatter_both(const float* __restrict__ feat_e, const float* __restrict__ feat_t,
                             const int* __restrict__ src, const int* __restrict__ dst,
                             float* __restrict__ agg_t, float* __restrict__ agg_e, int E) {
  int gid = blockIdx.x * blockDim.x + threadIdx.x;
  int wave = gid >> 6;
  int lane = gid & 63;
  int nw = (gridDim.x * blockDim.x) >> 6;
  for (int e = wave; e < E; e += nw) {
    int s = src[e], d = dst[e];
    float2 ve = *(const float2*)&feat_e[(size_t)s * H + lane * 2];
    float2 vt = *(const float2*)&feat_t[(size_t)d * H + lane * 2];
    float* at = &agg_t[(size_t)d * H + lane * 2];
    float* ae = &agg_e[(size_t)s * H + lane * 2];
    atomicAdd(at, ve.x);
    atomicAdd(at + 1, ve.y);
    atomicAdd(ae, vt.x);
    atomicAdd(ae + 1, vt.y);
  }
}

// ------------------------------------------------- fused mean + 2 GEMMs + bias (+ReLU)
// out[row,:] = act( (agg[row,:]/max(deg,1)) @ Wl + bias + xd[row,:] @ Wr )
// out may alias agg (block reads its rows into LDS before writing them).
template <bool RELU>
__global__ __launch_bounds__(256) void fused_sage(
    const float* __restrict__ agg, const float* __restrict__ deg,
    const float* __restrict__ xd,
    const float* __restrict__ Wl, const float* __restrict__ Wr,
    const float* __restrict__ bias,
    float* __restrict__ out, int n) {
  __shared__ float sA[64][132];  // 132 pad: float4-aligned rows, spread banks
  __shared__ float sX[64][132];
  const int t = threadIdx.x;
  const int tx = t & 31;   // col group (4 cols)
  const int ty = t >> 5;   // row group
  const int row0 = blockIdx.x * 64;

  // stage 64 rows of agg (pre-scaled by 1/deg) and xd into LDS
  for (int it = 0; it < 8; ++it) {
    int r = it * 8 + ty;
    int row = row0 + r;
    float4 va = make_float4(0.f, 0.f, 0.f, 0.f);
    float4 vx = va;
    float rd = 0.f;
    if (row < n) {
      rd = 1.0f / fmaxf(deg[row], 1.0f);
      va = *(const float4*)&agg[(size_t)row * H + tx * 4];
      vx = *(const float4*)&xd[(size_t)row * H + tx * 4];
    }
    va.x *= rd; va.y *= rd; va.z *= rd; va.w *= rd;
    *(float4*)&sA[r][tx * 4] = va;
    *(float4*)&sX[r][tx * 4] = vx;
  }
  __syncthreads();

  float4 bv = *(const float4*)&bias[tx * 4];
  float acc[8][4];
#pragma unroll
  for (int r = 0; r < 8; ++r) {
    acc[r][0] = bv.x; acc[r][1] = bv.y; acc[r][2] = bv.z; acc[r][3] = bv.w;
  }

  const int rbase = ty * 8;
#pragma unroll 4
  for (int k = 0; k < H; ++k) {
    float4 wl = *(const float4*)&Wl[k * H + tx * 4];
    float4 wr = *(const float4*)&Wr[k * H + tx * 4];
#pragma unroll
    for (int r = 0; r < 8; ++r) {
      float a = sA[rbase + r][k];  // broadcast read
      float x = sX[rbase + r][k];
      acc[r][0] += a * wl.x; acc[r][0] += x * wr.x;
      acc[r][1] += a * wl.y; acc[r][1] += x * wr.y;
      acc[r][2] += a * wl.z; acc[r][2] += x * wr.z;
      acc[r][3] += a * wl.w; acc[r][3] += x * wr.w;
    }
  }

#pragma unroll
  for (int r = 0; r < 8; ++r) {
    int row = row0 + rbase + r;
    if (row < n) {
      float4 v;
      v.x = acc[r][0]; v.y = acc[r][1]; v.z = acc[r][2]; v.w = acc[r][3];
      if (RELU) {
        v.x = fmaxf(v.x, 0.f); v.y = fmaxf(v.y, 0.f);
        v.z = fmaxf(v.z, 0.f); v.w = fmaxf(v.w, 0.f);
      }
      *(float4*)&out[(size_t)row * H + tx * 4] = v;
    }
  }
}

// ---------------------------------------------------------------- edge dot
__global__ void edge_dot(const float* __restrict__ ze, const float* __restrict__ zt,
                         const int* __restrict__ ls, const int* __restrict__ ld,
                         float* __restrict__ out, int L) {
  int i = blockIdx.x * blockDim.x + threadIdx.x;
  int s = gridDim.x * blockDim.x;
  for (; i < L; i += s) {
    const float4* a = (const float4*)&ze[(size_t)ls[i] * H];
    const float4* b = (const float4*)&zt[(size_t)ld[i] * H];
    float acc = 0.f;
#pragma unroll 8
    for (int j = 0; j < 32; ++j) {
      float4 va = a[j], vb = b[j];
      acc += va.x * vb.x + va.y * vb.y + va.z * vb.z + va.w * vb.w;
    }
    out[i] = acc;
  }
}

// ---------------------------------------------------------------- launch
extern "C" void kernel_launch(void* const* d_in, const int* in_sizes, int n_in,
                              void* d_out, int out_size, void* d_ws, size_t ws_size,
                              hipStream_t stream) {
  const float* x_e = (const float*)d_in[0];
  const float* x_t = (const float*)d_in[1];
  const int* src = (const int*)d_in[2];
  const int* dst = (const int*)d_in[3];
  const int* ls = (const int*)d_in[4];
  const int* ld = (const int*)d_in[5];
  const float* W1et_l = (const float*)d_in[6];
  const float* W1et_r = (const float*)d_in[7];
  const float* W1te_l = (const float*)d_in[8];
  const float* W1te_r = (const float*)d_in[9];
  const float* W2et_l = (const float*)d_in[10];
  const float* W2et_r = (const float*)d_in[11];
  const float* W2te_l = (const float*)d_in[12];
  const float* W2te_r = (const float*)d_in[13];
  const float* b1et = (const float*)d_in[14];
  const float* b1te = (const float*)d_in[15];
  const float* b2et = (const float*)d_in[16];
  const float* b2te = (const float*)d_in[17];

  const int n_e = in_sizes[0] / H;
  const int n_t = in_sizes[1] / H;
  const int E = in_sizes[2];
  const int L = in_sizes[4];
  float* out = (float*)d_out;

  const size_t fe = (size_t)n_e * H;
  const size_t ft = (size_t)n_t * H;
  float* ws = (float*)d_ws;
  float* agg_e = ws;             // [n_e,128]  later holds z_expert
  float* agg_t = agg_e + fe;     // [n_t,128]  later holds z_team
  float* deg_e = agg_t + ft;     // [n_e]
  float* deg_t = deg_e + n_e;    // [n_t]
  float* h_e = deg_t + n_t;      // [n_e,128]
  float* h_t = h_e + fe;         // [n_t,128]

  const dim3 blk(256);

  // 1. zero agg_e, agg_t, deg_e, deg_t (one contiguous span)
  zero_f32<<<2048, blk, 0, stream>>>(ws, fe + ft + n_e + n_t);
  // 2. degrees
  deg_kernel<<<1024, blk, 0, stream>>>(src, dst, deg_e, deg_t, E);
  // 3. layer-1 scatter (both directions)
  scatter_both<<<8192, blk, 0, stream>>>(x_e, x_t, src, dst, agg_t, agg_e, E);
  // 4. layer-1 dense, ReLU
  fused_sage<true><<<(n_t + 63) / 64, blk, 0, stream>>>(agg_t, deg_t, x_t, W1et_l, W1et_r, b1et, h_t, n_t);
  fused_sage<true><<<(n_e + 63) / 64, blk, 0, stream>>>(agg_e, deg_e, x_e, W1te_l, W1te_r, b1te, h_e, n_e);
  // 5. re-zero aggs
  zero_f32<<<2048, blk, 0, stream>>>(ws, fe + ft);
  // 6. layer-2 scatter
  scatter_both<<<8192, blk, 0, stream>>>(h_e, h_t, src, dst, agg_t, agg_e, E);
  // 7. layer-2 dense (in place: z overwrites agg)
  fused_sage<false><<<(n_t + 63) / 64, blk, 0, stream>>>(agg_t, deg_t, h_t, W2et_l, W2et_r, b2et, agg_t, n_t);
  fused_sage<false><<<(n_e + 63) / 64, blk, 0, stream>>>(agg_e, deg_e, h_e, W2te_l, W2te_r, b2te, agg_e, n_e);
  // 8. edge dot readout
  edge_dot<<<2048, blk, 0, stream>>>(agg_e, agg_t, ls, ld, out, L);
}

// Round 2
// 744.705 us; speedup vs baseline: 3.3243x; 3.3243x over previous
//
#include <hip/hip_runtime.h>

#define H 128

// ---------------------------------------------------------------- zero ints
__global__ void zero_i32(int* __restrict__ p, int n) {
  int i = blockIdx.x * blockDim.x + threadIdx.x;
  int s = gridDim.x * blockDim.x;
  for (; i < n; i += s) p[i] = 0;
}

// ---------------------------------------------------------------- histogram
__global__ void hist_kernel(const int* __restrict__ src, const int* __restrict__ dst,
                            int* __restrict__ cnt_e, int* __restrict__ cnt_t, int E) {
  int i = blockIdx.x * blockDim.x + threadIdx.x;
  int s = gridDim.x * blockDim.x;
  for (; i < E; i += s) {
    atomicAdd(&cnt_t[dst[i]], 1);
    atomicAdd(&cnt_e[src[i]], 1);
  }
}

// ---------------------------------------------------------------- 3-phase exclusive scan
__global__ void scan1(const int* __restrict__ in, int* __restrict__ out,
                      int* __restrict__ part, int n) {
  __shared__ int s[256];
  int t = threadIdx.x;
  int i = blockIdx.x * 256 + t;
  int v = (i < n) ? in[i] : 0;
  s[t] = v;
  __syncthreads();
  for (int off = 1; off < 256; off <<= 1) {
    int tmp = (t >= off) ? s[t - off] : 0;
    __syncthreads();
    s[t] += tmp;
    __syncthreads();
  }
  if (i < n) out[i] = s[t] - v;  // exclusive
  if (t == 255) part[blockIdx.x] = s[255];
}

__global__ void scan2(int* __restrict__ part, int nb) {
  __shared__ int s[256];
  __shared__ int carry;
  int t = threadIdx.x;
  if (t == 0) carry = 0;
  __syncthreads();
  for (int base = 0; base < nb; base += 256) {
    int i = base + t;
    int v = (i < nb) ? part[i] : 0;
    s[t] = v;
    __syncthreads();
    for (int off = 1; off < 256; off <<= 1) {
      int tmp = (t >= off) ? s[t - off] : 0;
      __syncthreads();
      s[t] += tmp;
      __syncthreads();
    }
    if (i < nb) part[i] = s[t] - v + carry;
    __syncthreads();
    if (t == 255) carry += s[255];
    __syncthreads();
  }
}

__global__ void scan3(int* __restrict__ out, const int* __restrict__ part, int n) {
  int i = blockIdx.x * 256 + threadIdx.x;
  if (i < n) out[i] += part[blockIdx.x];
}

// ---------------------------------------------------------------- CSR fill
__global__ void fill_kernel(const int* __restrict__ src, const int* __restrict__ dst,
                            const int* __restrict__ off_e, const int* __restrict__ off_t,
                            int* __restrict__ cur_e, int* __restrict__ cur_t,
                            int* __restrict__ adj_e, int* __restrict__ adj_t, int E) {
  int i = blockIdx.x * blockDim.x + threadIdx.x;
  int st = gridDim.x * blockDim.x;
  for (; i < E; i += st) {
    int s = src[i], d = dst[i];
    int pt = off_t[d] + atomicAdd(&cur_t[d], 1);
    adj_t[pt] = s;
    int pe = off_e[s] + atomicAdd(&cur_e[s], 1);
    adj_e[pe] = d;
  }
}

// ---------------------------------------------------------------- pull mean
// one wave per destination node; lane handles 2 floats of the 128-wide row.
__global__ void pull_mean(const float* __restrict__ feat, const int* __restrict__ off,
                          const int* __restrict__ adj, float* __restrict__ out, int n) {
  int gid = blockIdx.x * blockDim.x + threadIdx.x;
  int wave = gid >> 6;
  int lane = gid & 63;
  int nw = (gridDim.x * blockDim.x) >> 6;
  for (int v = wave; v < n; v += nw) {
    int s = off[v], e = off[v + 1];
    float2 a0 = make_float2(0.f, 0.f), a1 = a0, a2 = a0, a3 = a0;
    int i = s;
    for (; i + 4 <= e; i += 4) {
      int u0 = adj[i], u1 = adj[i + 1], u2 = adj[i + 2], u3 = adj[i + 3];
      float2 v0 = *(const float2*)&feat[(size_t)u0 * H + lane * 2];
      float2 v1 = *(const float2*)&feat[(size_t)u1 * H + lane * 2];
      float2 v2 = *(const float2*)&feat[(size_t)u2 * H + lane * 2];
      float2 v3 = *(const float2*)&feat[(size_t)u3 * H + lane * 2];
      a0.x += v0.x; a0.y += v0.y;
      a1.x += v1.x; a1.y += v1.y;
      a2.x += v2.x; a2.y += v2.y;
      a3.x += v3.x; a3.y += v3.y;
    }
    for (; i < e; ++i) {
      int u = adj[i];
      float2 v0 = *(const float2*)&feat[(size_t)u * H + lane * 2];
      a0.x += v0.x; a0.y += v0.y;
    }
    float rd = 1.0f / fmaxf((float)(e - s), 1.0f);
    float2 r;
    r.x = ((a0.x + a1.x) + (a2.x + a3.x)) * rd;
    r.y = ((a0.y + a1.y) + (a2.y + a3.y)) * rd;
    *(float2*)&out[(size_t)v * H + lane * 2] = r;
  }
}

// ------------------------------------------------- fused 2 GEMMs + bias (+ReLU)
// out[row,:] = act( agg[row,:] @ Wl + bias + xd[row,:] @ Wr ), out may alias agg
template <bool RELU>
__global__ __launch_bounds__(256) void fused_sage(
    const float* __restrict__ agg, const float* __restrict__ xd,
    const float* __restrict__ Wl, const float* __restrict__ Wr,
    const float* __restrict__ bias,
    float* __restrict__ out, int n) {
  __shared__ float sA[64][132];
  __shared__ float sX[64][132];
  const int t = threadIdx.x;
  const int tx = t & 31;
  const int ty = t >> 5;
  const int row0 = blockIdx.x * 64;

  for (int it = 0; it < 8; ++it) {
    int r = it * 8 + ty;
    int row = row0 + r;
    float4 va = make_float4(0.f, 0.f, 0.f, 0.f);
    float4 vx = va;
    if (row < n) {
      va = *(const float4*)&agg[(size_t)row * H + tx * 4];
      vx = *(const float4*)&xd[(size_t)row * H + tx * 4];
    }
    *(float4*)&sA[r][tx * 4] = va;
    *(float4*)&sX[r][tx * 4] = vx;
  }
  __syncthreads();

  float4 bv = *(const float4*)&bias[tx * 4];
  float acc[8][4];
#pragma unroll
  for (int r = 0; r < 8; ++r) {
    acc[r][0] = bv.x; acc[r][1] = bv.y; acc[r][2] = bv.z; acc[r][3] = bv.w;
  }

  const int rbase = ty * 8;
#pragma unroll 4
  for (int k = 0; k < H; ++k) {
    float4 wl = *(const float4*)&Wl[k * H + tx * 4];
    float4 wr = *(const float4*)&Wr[k * H + tx * 4];
#pragma unroll
    for (int r = 0; r < 8; ++r) {
      float a = sA[rbase + r][k];
      float x = sX[rbase + r][k];
      acc[r][0] += a * wl.x; acc[r][0] += x * wr.x;
      acc[r][1] += a * wl.y; acc[r][1] += x * wr.y;
      acc[r][2] += a * wl.z; acc[r][2] += x * wr.z;
      acc[r][3] += a * wl.w; acc[r][3] += x * wr.w;
    }
  }

#pragma unroll
  for (int r = 0; r < 8; ++r) {
    int row = row0 + rbase + r;
    if (row < n) {
      float4 v;
      v.x = acc[r][0]; v.y = acc[r][1]; v.z = acc[r][2]; v.w = acc[r][3];
      if (RELU) {
        v.x = fmaxf(v.x, 0.f); v.y = fmaxf(v.y, 0.f);
        v.z = fmaxf(v.z, 0.f); v.w = fmaxf(v.w, 0.f);
      }
      *(float4*)&out[(size_t)row * H + tx * 4] = v;
    }
  }
}

// ---------------------------------------------------------------- edge dot (wave per edge)
__global__ void edge_dot(const float* __restrict__ ze, const float* __restrict__ zt,
                         const int* __restrict__ ls, const int* __restrict__ ld,
                         float* __restrict__ out, int L) {
  int gid = blockIdx.x * blockDim.x + threadIdx.x;
  int w = gid >> 6;
  int lane = gid & 63;
  if (w >= L) return;
  int a = ls[w], b = ld[w];
  float2 va = *(const float2*)&ze[(size_t)a * H + lane * 2];
  float2 vb = *(const float2*)&zt[(size_t)b * H + lane * 2];
  float p = va.x * vb.x + va.y * vb.y;
#pragma unroll
  for (int o = 32; o; o >>= 1) p += __shfl_down(p, o);
  if (lane == 0) out[w] = p;
}

// ---------------------------------------------------------------- launch
extern "C" void kernel_launch(void* const* d_in, const int* in_sizes, int n_in,
                              void* d_out, int out_size, void* d_ws, size_t ws_size,
                              hipStream_t stream) {
  const float* x_e = (const float*)d_in[0];
  const float* x_t = (const float*)d_in[1];
  const int* src = (const int*)d_in[2];
  const int* dst = (const int*)d_in[3];
  const int* ls = (const int*)d_in[4];
  const int* ld = (const int*)d_in[5];
  const float* W1et_l = (const float*)d_in[6];
  const float* W1et_r = (const float*)d_in[7];
  const float* W1te_l = (const float*)d_in[8];
  const float* W1te_r = (const float*)d_in[9];
  const float* W2et_l = (const float*)d_in[10];
  const float* W2et_r = (const float*)d_in[11];
  const float* W2te_l = (const float*)d_in[12];
  const float* W2te_r = (const float*)d_in[13];
  const float* b1et = (const float*)d_in[14];
  const float* b1te = (const float*)d_in[15];
  const float* b2et = (const float*)d_in[16];
  const float* b2te = (const float*)d_in[17];

  const int n_e = in_sizes[0] / H;
  const int n_t = in_sizes[1] / H;
  const int E = in_sizes[2];
  const int L = in_sizes[4];
  float* out = (float*)d_out;

  const size_t fe = (size_t)n_e * H;
  const size_t ft = (size_t)n_t * H;
  float* ws = (float*)d_ws;
  // float buffers
  float* bufA_e = ws;              // layer1 agg -> h_expert (in place)
  float* bufA_t = bufA_e + fe;     // layer1 agg -> h_team
  float* bufB_e = bufA_t + ft;     // layer2 agg -> z_expert
  float* bufB_t = bufB_e + fe;     // layer2 agg -> z_team
  // int buffers
  int* ib = (int*)(bufB_t + ft);
  int* cnt_t = ib;                 // n_t+1 (also cursor after re-zero)
  int* cnt_e = cnt_t + (n_t + 1);  // n_e+1
  int* off_t = cnt_e + (n_e + 1);  // n_t+1
  int* off_e = off_t + (n_t + 1);  // n_e+1
  int* part = off_e + (n_e + 1);   // 1024
  int* adj_t = part + 1024;        // E  (expert srcs bucketed by team)
  int* adj_e = adj_t + E;          // E  (team dsts bucketed by expert)

  const dim3 blk(256);

  // ---- CSR build
  zero_i32<<<256, blk, 0, stream>>>(cnt_t, (n_t + 1) + (n_e + 1));
  hist_kernel<<<1024, blk, 0, stream>>>(src, dst, cnt_e, cnt_t, E);
  int nbt = (n_t + 1 + 255) / 256;
  int nbe = (n_e + 1 + 255) / 256;
  scan1<<<nbt, blk, 0, stream>>>(cnt_t, off_t, part, n_t + 1);
  scan2<<<1, blk, 0, stream>>>(part, nbt);
  scan3<<<nbt, blk, 0, stream>>>(off_t, part, n_t + 1);
  scan1<<<nbe, blk, 0, stream>>>(cnt_e, off_e, part, n_e + 1);
  scan2<<<1, blk, 0, stream>>>(part, nbe);
  scan3<<<nbe, blk, 0, stream>>>(off_e, part, n_e + 1);
  zero_i32<<<256, blk, 0, stream>>>(cnt_t, (n_t + 1) + (n_e + 1));  // cursors
  fill_kernel<<<1024, blk, 0, stream>>>(src, dst, off_e, off_t, cnt_e, cnt_t, adj_e, adj_t, E);

  // ---- layer 1: pull-mean then fused dense (in place), ReLU
  pull_mean<<<(n_t + 3) / 4, blk, 0, stream>>>(x_e, off_t, adj_t, bufA_t, n_t);
  pull_mean<<<(n_e + 3) / 4, blk, 0, stream>>>(x_t, off_e, adj_e, bufA_e, n_e);
  fused_sage<true><<<(n_t + 63) / 64, blk, 0, stream>>>(bufA_t, x_t, W1et_l, W1et_r, b1et, bufA_t, n_t);
  fused_sage<true><<<(n_e + 63) / 64, blk, 0, stream>>>(bufA_e, x_e, W1te_l, W1te_r, b1te, bufA_e, n_e);

  // ---- layer 2
  pull_mean<<<(n_t + 3) / 4, blk, 0, stream>>>(bufA_e, off_t, adj_t, bufB_t, n_t);
  pull_mean<<<(n_e + 3) / 4, blk, 0, stream>>>(bufA_t, off_e, adj_e, bufB_e, n_e);
  fused_sage<false><<<(n_t + 63) / 64, blk, 0, stream>>>(bufB_t, bufA_t, W2et_l, W2et_r, b2et, bufB_t, n_t);
  fused_sage<false><<<(n_e + 63) / 64, blk, 0, stream>>>(bufB_e, bufA_e, W2te_l, W2te_r, b2te, bufB_e, n_e);

  // ---- edge dot readout
  edge_dot<<<((size_t)L * 64 + 255) / 256, blk, 0, stream>>>(bufB_e, bufB_t, ls, ld, out, L);
}

// Round 3
// 455.977 us; speedup vs baseline: 5.4292x; 1.6332x over previous
//
#include <hip/hip_runtime.h>

#define H 128
typedef unsigned short ushort_t;
typedef unsigned int uint_t;
using s16x8 = __attribute__((ext_vector_type(8))) short;
using f32x4 = __attribute__((ext_vector_type(4))) float;

// ---------------------------------------------------------------- bf16 helpers
__device__ __forceinline__ ushort_t f2bf(float x) {  // RNE
  uint_t u = __float_as_uint(x);
  return (ushort_t)((u + 0x7fff + ((u >> 16) & 1)) >> 16);
}
__device__ __forceinline__ float bflo(uint_t u) { return __uint_as_float(u << 16); }
__device__ __forceinline__ float bfhi(uint_t u) { return __uint_as_float(u & 0xffff0000u); }

// ---------------------------------------------------------------- async global->LDS 16B
__device__ __forceinline__ void gload_lds16(const void* g, void* l) {
  __builtin_amdgcn_global_load_lds(
      (const __attribute__((address_space(1))) unsigned int*)(unsigned long long)g,
      (__attribute__((address_space(3))) unsigned int*)(unsigned int)(unsigned long long)l,
      16, 0, 0);
}

// ---------------------------------------------------------------- zero ints
__global__ void zero_i32(int* __restrict__ p, int n) {
  int i = blockIdx.x * blockDim.x + threadIdx.x;
  int s = gridDim.x * blockDim.x;
  for (; i < n; i += s) p[i] = 0;
}

// ---------------------------------------------------------------- fp32 -> bf16 copy
__global__ void cvt_bf16(const float* __restrict__ in, ushort_t* __restrict__ out, size_t n4) {
  size_t i = (size_t)blockIdx.x * blockDim.x + threadIdx.x;
  size_t s = (size_t)gridDim.x * blockDim.x;
  for (; i < n4; i += s) {
    float4 v = ((const float4*)in)[i];
    uint2 r;
    r.x = (uint_t)f2bf(v.x) | ((uint_t)f2bf(v.y) << 16);
    r.y = (uint_t)f2bf(v.z) | ((uint_t)f2bf(v.w) << 16);
    ((uint2*)out)[i] = r;
  }
}

// ------------------------------------------- W pair -> MFMA B-fragment layout
// dst[ks][nf][lane][j]: B[k][n] with k = ks*32 + (lane>>4)*8 + j, n = nf*16 + (lane&15)
// k<128 from Wl, else from Wr. 32768 bf16 per pair.
__global__ void build_wfrag(const float* __restrict__ Wl, const float* __restrict__ Wr,
                            ushort_t* __restrict__ dst) {
  int i = blockIdx.x * 256 + threadIdx.x;  // 0..32767
  int j = i & 7;
  int lane = (i >> 3) & 63;
  int nf = (i >> 9) & 7;
  int ks = i >> 12;
  int k = ks * 32 + (lane >> 4) * 8 + j;
  int nn = nf * 16 + (lane & 15);
  float v = (k < H) ? Wl[k * H + nn] : Wr[(k - H) * H + nn];
  dst[i] = f2bf(v);
}

// ---------------------------------------------------------------- histogram
__global__ void hist_kernel(const int* __restrict__ src, const int* __restrict__ dst,
                            int* __restrict__ cnt_e, int* __restrict__ cnt_t, int E) {
  int i = blockIdx.x * blockDim.x + threadIdx.x;
  int s = gridDim.x * blockDim.x;
  for (; i < E; i += s) {
    atomicAdd(&cnt_t[dst[i]], 1);
    atomicAdd(&cnt_e[src[i]], 1);
  }
}

// ---------------------------------------------------------------- 3-phase exclusive scan
__global__ void scan1(const int* __restrict__ in, int* __restrict__ out,
                      int* __restrict__ part, int n) {
  __shared__ int s[256];
  int t = threadIdx.x;
  int i = blockIdx.x * 256 + t;
  int v = (i < n) ? in[i] : 0;
  s[t] = v;
  __syncthreads();
  for (int off = 1; off < 256; off <<= 1) {
    int tmp = (t >= off) ? s[t - off] : 0;
    __syncthreads();
    s[t] += tmp;
    __syncthreads();
  }
  if (i < n) out[i] = s[t] - v;
  if (t == 255) part[blockIdx.x] = s[255];
}

__global__ void scan2(int* __restrict__ part, int nb) {
  __shared__ int s[256];
  __shared__ int carry;
  int t = threadIdx.x;
  if (t == 0) carry = 0;
  __syncthreads();
  for (int base = 0; base < nb; base += 256) {
    int i = base + t;
    int v = (i < nb) ? part[i] : 0;
    s[t] = v;
    __syncthreads();
    for (int off = 1; off < 256; off <<= 1) {
      int tmp = (t >= off) ? s[t - off] : 0;
      __syncthreads();
      s[t] += tmp;
      __syncthreads();
    }
    if (i < nb) part[i] = s[t] - v + carry;
    __syncthreads();
    if (t == 255) carry += s[255];
    __syncthreads();
  }
}

__global__ void scan3(int* __restrict__ out, const int* __restrict__ part, int n) {
  int i = blockIdx.x * 256 + threadIdx.x;
  if (i < n) out[i] += part[blockIdx.x];
}

// ---------------------------------------------------------------- CSR fill
__global__ void fill_kernel(const int* __restrict__ src, const int* __restrict__ dst,
                            const int* __restrict__ off_e, const int* __restrict__ off_t,
                            int* __restrict__ cur_e, int* __restrict__ cur_t,
                            int* __restrict__ adj_e, int* __restrict__ adj_t, int E) {
  int i = blockIdx.x * blockDim.x + threadIdx.x;
  int st = gridDim.x * blockDim.x;
  for (; i < E; i += st) {
    int s = src[i], d = dst[i];
    int pt = off_t[d] + atomicAdd(&cur_t[d], 1);
    adj_t[pt] = s;
    int pe = off_e[s] + atomicAdd(&cur_e[s], 1);
    adj_e[pe] = d;
  }
}

// ---------------------------------------------------------------- pull mean (bf16 feats)
// one wave per node; lane handles one uint (2 bf16) of the 256B row.
__global__ void pull_mean_bf16(const ushort_t* __restrict__ feat, const int* __restrict__ off,
                               const int* __restrict__ adj, ushort_t* __restrict__ out, int n) {
  int gid = blockIdx.x * blockDim.x + threadIdx.x;
  int wave = gid >> 6;
  int lane = gid & 63;
  int nw = (gridDim.x * blockDim.x) >> 6;
  const uint_t* f = (const uint_t*)feat;
  uint_t* o = (uint_t*)out;
  for (int v = wave; v < n; v += nw) {
    int s = off[v], e = off[v + 1];
    float ax0 = 0.f, ay0 = 0.f, ax1 = 0.f, ay1 = 0.f;
    int i = s;
    for (; i + 2 <= e; i += 2) {
      uint_t u0 = f[(size_t)adj[i] * 64 + lane];
      uint_t u1 = f[(size_t)adj[i + 1] * 64 + lane];
      ax0 += bflo(u0); ay0 += bfhi(u0);
      ax1 += bflo(u1); ay1 += bfhi(u1);
    }
    if (i < e) {
      uint_t u0 = f[(size_t)adj[i] * 64 + lane];
      ax0 += bflo(u0); ay0 += bfhi(u0);
    }
    float rd = 1.0f / fmaxf((float)(e - s), 1.0f);
    o[(size_t)v * 64 + lane] = (uint_t)f2bf((ax0 + ax1) * rd) | ((uint_t)f2bf((ay0 + ay1) * rd) << 16);
  }
}

// ---------------------------------------------------------------- fused MFMA GEMM
// out[row,:] = act( [agg[row,:] | xd[row,:]] @ [Wl;Wr] + bias )  -- K=256, N=128, bf16 in/out
// B (the stacked W) lives entirely in registers, loaded once per persistent block.
// A staged 64 rows/tile in LDS via global_load_lds with XOR-swizzled source.
template <bool RELU>
__global__ __launch_bounds__(256, 2) void gemm_mfma(
    const ushort_t* __restrict__ agg, const ushort_t* __restrict__ xd,
    const ushort_t* __restrict__ wfrag, const float* __restrict__ bias,
    ushort_t* __restrict__ out, int n) {
  __shared__ __align__(16) ushort_t sA[64 * 128];
  __shared__ __align__(16) ushort_t sX[64 * 128];
  const int t = threadIdx.x;
  const int lane = t & 63;
  const int wid = t >> 6;
  const int mrow = (wid >> 1) * 32;   // wave's 32 output rows
  const int nhalf = (wid & 1) * 64;   // wave's 64 output cols

  // B fragments in registers: 8 K-steps x 4 N-frags
  s16x8 B[8][4];
#pragma unroll
  for (int ks = 0; ks < 8; ++ks)
#pragma unroll
    for (int nfi = 0; nfi < 4; ++nfi)
      B[ks][nfi] = *(const s16x8*)(wfrag + (size_t)(((ks << 3) | ((nhalf >> 4) + nfi)) << 9) + (lane << 3));

  float bv[4];
#pragma unroll
  for (int nfi = 0; nfi < 4; ++nfi) bv[nfi] = bias[nhalf + nfi * 16 + (lane & 15)];

  const int lrow = lane >> 4;          // row within 4-row staging region
  const int pbyte = (lane & 15) << 4;  // byte pos within 256B row

  const int ntiles = (n + 63) >> 6;
  for (int tile = blockIdx.x; tile < ntiles; tile += gridDim.x) {
    const int row0 = tile << 6;
    // stage: 32 regions of 4 rows x 256B; this wave does regions wid*8..wid*8+7
#pragma unroll
    for (int i = 0; i < 8; ++i) {
      int reg = (wid << 3) + i;
      int rr = ((reg & 15) << 2) + lrow;
      int row = row0 + rr;
      row = row < n ? row : n - 1;
      int pp = pbyte ^ ((rr & 7) << 4);  // pre-swizzled source => swizzled LDS layout
      const ushort_t* src = (reg < 16 ? agg : xd) + (size_t)row * H + (pp >> 1);
      ushort_t* ldst = (reg < 16 ? sA : sX) + ((reg & 15) << 9);
      gload_lds16(src, ldst);
    }
    __syncthreads();

    f32x4 acc[2][4];
#pragma unroll
    for (int mi = 0; mi < 2; ++mi)
#pragma unroll
      for (int nfi = 0; nfi < 4; ++nfi) {
        f32x4 c = {bv[nfi], bv[nfi], bv[nfi], bv[nfi]};
        acc[mi][nfi] = c;
      }

    const int rr0 = mrow + (lane & 15);
    const int rr1 = rr0 + 16;
    const int kx = (lane >> 4) << 4;
    const int sw = (rr0 & 7) << 4;  // rr1 has same low-3 row bits
#pragma unroll
    for (int ks = 0; ks < 8; ++ks) {
      const ushort_t* base = (ks < 4) ? sA : sX;
      const int kb = (ks & 3) << 6;
      s16x8 a0 = *(const s16x8*)((const char*)base + rr0 * 256 + ((kb | kx) ^ sw));
      s16x8 a1 = *(const s16x8*)((const char*)base + rr1 * 256 + ((kb | kx) ^ sw));
#pragma unroll
      for (int nfi = 0; nfi < 4; ++nfi) {
        acc[0][nfi] = __builtin_amdgcn_mfma_f32_16x16x32_bf16(a0, B[ks][nfi], acc[0][nfi], 0, 0, 0);
        acc[1][nfi] = __builtin_amdgcn_mfma_f32_16x16x32_bf16(a1, B[ks][nfi], acc[1][nfi], 0, 0, 0);
      }
    }

    // epilogue: C/D layout col = lane&15, row = (lane>>4)*4 + r
#pragma unroll
    for (int mi = 0; mi < 2; ++mi) {
      int rbase = row0 + mrow + mi * 16 + ((lane >> 4) << 2);
#pragma unroll
      for (int r = 0; r < 4; ++r) {
        int row = rbase + r;
        if (row < n) {
#pragma unroll
          for (int nfi = 0; nfi < 4; ++nfi) {
            float v = acc[mi][nfi][r];
            if (RELU) v = fmaxf(v, 0.f);
            out[(size_t)row * H + nhalf + nfi * 16 + (lane & 15)] = f2bf(v);
          }
        }
      }
    }
    __syncthreads();
  }
}

// ---------------------------------------------------------------- edge dot (bf16 z)
__global__ void edge_dot_bf16(const ushort_t* __restrict__ ze, const ushort_t* __restrict__ zt,
                              const int* __restrict__ ls, const int* __restrict__ ld,
                              float* __restrict__ out, int L) {
  int gid = blockIdx.x * blockDim.x + threadIdx.x;
  int w = gid >> 6;
  int lane = gid & 63;
  if (w >= L) return;
  uint_t ua = ((const uint_t*)ze)[(size_t)ls[w] * 64 + lane];
  uint_t ub = ((const uint_t*)zt)[(size_t)ld[w] * 64 + lane];
  float p = bflo(ua) * bflo(ub) + bfhi(ua) * bfhi(ub);
#pragma unroll
  for (int o = 32; o; o >>= 1) p += __shfl_down(p, o);
  if (lane == 0) out[w] = p;
}

// ---------------------------------------------------------------- launch
extern "C" void kernel_launch(void* const* d_in, const int* in_sizes, int n_in,
                              void* d_out, int out_size, void* d_ws, size_t ws_size,
                              hipStream_t stream) {
  const float* x_e = (const float*)d_in[0];
  const float* x_t = (const float*)d_in[1];
  const int* src = (const int*)d_in[2];
  const int* dst = (const int*)d_in[3];
  const int* ls = (const int*)d_in[4];
  const int* ld = (const int*)d_in[5];
  const float* W1et_l = (const float*)d_in[6];
  const float* W1et_r = (const float*)d_in[7];
  const float* W1te_l = (const float*)d_in[8];
  const float* W1te_r = (const float*)d_in[9];
  const float* W2et_l = (const float*)d_in[10];
  const float* W2et_r = (const float*)d_in[11];
  const float* W2te_l = (const float*)d_in[12];
  const float* W2te_r = (const float*)d_in[13];
  const float* b1et = (const float*)d_in[14];
  const float* b1te = (const float*)d_in[15];
  const float* b2et = (const float*)d_in[16];
  const float* b2te = (const float*)d_in[17];

  const int n_e = in_sizes[0] / H;
  const int n_t = in_sizes[1] / H;
  const int E = in_sizes[2];
  const int L = in_sizes[4];
  float* out = (float*)d_out;

  const size_t fe = (size_t)n_e * H;
  const size_t ft = (size_t)n_t * H;
  ushort_t* us = (ushort_t*)d_ws;
  ushort_t* xb_e = us;               // fe  (x_expert bf16)
  ushort_t* xb_t = xb_e + fe;        // ft
  ushort_t* agg_e = xb_t + ft;       // fe  (agg both layers; z_expert at end)
  ushort_t* agg_t = agg_e + fe;      // ft  (… z_team at end)
  ushort_t* h_e = agg_t + ft;        // fe
  ushort_t* h_t = h_e + fe;          // ft
  ushort_t* wf1et = h_t + ft;        // 32768 each
  ushort_t* wf1te = wf1et + 32768;
  ushort_t* wf2et = wf1te + 32768;
  ushort_t* wf2te = wf2et + 32768;
  int* ib = (int*)(wf2te + 32768);
  int* cnt_t = ib;                  // n_t+1
  int* cnt_e = cnt_t + (n_t + 1);   // n_e+1
  int* off_t = cnt_e + (n_e + 1);   // n_t+1
  int* off_e = off_t + (n_t + 1);   // n_e+1
  int* part = off_e + (n_e + 1);    // 1024
  int* adj_t = part + 1024;         // E
  int* adj_e = adj_t + E;           // E

  const dim3 blk(256);

  // ---- bf16 conversions
  cvt_bf16<<<2048, blk, 0, stream>>>(x_e, xb_e, fe / 4);
  cvt_bf16<<<2048, blk, 0, stream>>>(x_t, xb_t, ft / 4);
  build_wfrag<<<128, blk, 0, stream>>>(W1et_l, W1et_r, wf1et);
  build_wfrag<<<128, blk, 0, stream>>>(W1te_l, W1te_r, wf1te);
  build_wfrag<<<128, blk, 0, stream>>>(W2et_l, W2et_r, wf2et);
  build_wfrag<<<128, blk, 0, stream>>>(W2te_l, W2te_r, wf2te);

  // ---- CSR build
  zero_i32<<<256, blk, 0, stream>>>(cnt_t, (n_t + 1) + (n_e + 1));
  hist_kernel<<<1024, blk, 0, stream>>>(src, dst, cnt_e, cnt_t, E);
  int nbt = (n_t + 1 + 255) / 256;
  int nbe = (n_e + 1 + 255) / 256;
  scan1<<<nbt, blk, 0, stream>>>(cnt_t, off_t, part, n_t + 1);
  scan2<<<1, blk, 0, stream>>>(part, nbt);
  scan3<<<nbt, blk, 0, stream>>>(off_t, part, n_t + 1);
  scan1<<<nbe, blk, 0, stream>>>(cnt_e, off_e, part, n_e + 1);
  scan2<<<1, blk, 0, stream>>>(part, nbe);
  scan3<<<nbe, blk, 0, stream>>>(off_e, part, n_e + 1);
  zero_i32<<<256, blk, 0, stream>>>(cnt_t, (n_t + 1) + (n_e + 1));
  fill_kernel<<<1024, blk, 0, stream>>>(src, dst, off_e, off_t, cnt_e, cnt_t, adj_e, adj_t, E);

  const int gt = min((n_t + 63) / 64, 512);
  const int ge = min((n_e + 63) / 64, 512);

  // ---- layer 1
  pull_mean_bf16<<<(n_t + 3) / 4, blk, 0, stream>>>(xb_e, off_t, adj_t, agg_t, n_t);
  pull_mean_bf16<<<(n_e + 3) / 4, blk, 0, stream>>>(xb_t, off_e, adj_e, agg_e, n_e);
  gemm_mfma<true><<<gt, blk, 0, stream>>>(agg_t, xb_t, wf1et, b1et, h_t, n_t);
  gemm_mfma<true><<<ge, blk, 0, stream>>>(agg_e, xb_e, wf1te, b1te, h_e, n_e);

  // ---- layer 2 (agg buffers reused; GEMM2 writes z in place over agg)
  pull_mean_bf16<<<(n_t + 3) / 4, blk, 0, stream>>>(h_e, off_t, adj_t, agg_t, n_t);
  pull_mean_bf16<<<(n_e + 3) / 4, blk, 0, stream>>>(h_t, off_e, adj_e, agg_e, n_e);
  gemm_mfma<false><<<gt, blk, 0, stream>>>(agg_t, h_t, wf2et, b2et, agg_t, n_t);
  gemm_mfma<false><<<ge, blk, 0, stream>>>(agg_e, h_e, wf2te, b2te, agg_e, n_e);

  // ---- edge dot readout
  edge_dot_bf16<<<((size_t)L * 64 + 255) / 256, blk, 0, stream>>>(agg_e, agg_t, ls, ld, out, L);
}